// Round 4
// baseline (731.374 us; speedup 1.0000x reference)
//
#include <hip/hip_runtime.h>
#include <math.h>

// ---------------------------------------------------------------------------
// Fused transformer block w/ MoE (B=2,T=2048,C=1024,H=16,D=64,E=8,topK=2)
// Round 4: XCD-chunked tile swizzle (expert==XCD for MoE GEMMs), pj+combine
// fused via f32 atomicAdd, 2-phase dbuf K-loop, exp2 gelu/softmax.
// ---------------------------------------------------------------------------

typedef __bf16 b16v8 __attribute__((ext_vector_type(8)));
typedef float f32x4 __attribute__((ext_vector_type(4)));

#define MFMA(a, b, c) __builtin_amdgcn_mfma_f32_16x16x32_bf16(a, b, c, 0, 0, 0)

#define GLOAD_LDS16(g, l)                                          \
  __builtin_amdgcn_global_load_lds(                                \
      (const __attribute__((address_space(1))) void*)(g),          \
      (__attribute__((address_space(3))) void*)(l), 16, 0, 0)

// raw barrier with manual vmcnt drain; memory-clobber fences on both sides
#define SYNC_VM0()                                       \
  do {                                                   \
    asm volatile("s_waitcnt vmcnt(0)" ::: "memory");     \
    __builtin_amdgcn_s_barrier();                        \
    asm volatile("" ::: "memory");                       \
  } while (0)

constexpr int Bc = 2, Tc = 2048, Cc = 1024, Hc = 16, Dc = 64;
constexpr int Nc = Bc * Tc;       // 4096 tokens
constexpr int HIDc = 4096;        // 4*C
constexpr int Ec = 8;
constexpr int NPAIR = Nc * 2;     // 8192 (always: top-2 per token)
constexpr float LOG2E = 1.4426950408889634f;

__device__ inline unsigned short f32_bf16(float f) {
  union { float f; unsigned u; } x; x.f = f;
  unsigned r = x.u + 0x7fffu + ((x.u >> 16) & 1u);   // RNE
  return (unsigned short)(r >> 16);
}

// gelu(x) = x * sigmoid(1.595769122*(x+0.044715x^3));  exp2-domain, 1 exp + 1 rcp
__device__ inline float gelu_f(float x) {
  float t = 2.3021188f * x * (1.f + 0.044715f * x * x);   // 1.5957691*log2(e)
  float e = __builtin_amdgcn_exp2f(-t);
  return x * __builtin_amdgcn_rcpf(1.f + e);
}

// ---------------------------------------------------------------------------
// Transpose+convert: src f32 [batch][K][N] -> dst bf16 [batch][N][K]
// ---------------------------------------------------------------------------
__global__ __launch_bounds__(256) void convT_kernel(
    const float* __restrict__ src, unsigned short* __restrict__ dst,
    int K, int N) {
  const size_t sb = (size_t)blockIdx.z * K * N;
  const int n0 = blockIdx.x * 32, k0 = blockIdx.y * 32;
  __shared__ float t[32][33];
  const int tx = threadIdx.x & 31, ty = threadIdx.x >> 5;  // ty 0..7
#pragma unroll
  for (int j = 0; j < 4; ++j)
    t[ty + j * 8][tx] = src[sb + (size_t)(k0 + ty + j * 8) * N + n0 + tx];
  __syncthreads();
#pragma unroll
  for (int j = 0; j < 4; ++j)
    dst[sb + (size_t)(n0 + ty + j * 8) * K + k0 + tx] = f32_bf16(t[tx][ty + j * 8]);
}

// ---------------------------------------------------------------------------
// LayerNorm (f32 in -> bf16 out). One block per row, 256 threads.
// ---------------------------------------------------------------------------
__global__ __launch_bounds__(256) void ln1_kernel(
    const float* __restrict__ x, const float* __restrict__ g,
    const float* __restrict__ b, unsigned short* __restrict__ out) {
  const int row = blockIdx.x;
  const int tid = threadIdx.x;
  const float* xr = x + (size_t)row * Cc;
  float v[4]; float s = 0.f, q = 0.f;
#pragma unroll
  for (int j = 0; j < 4; ++j) { v[j] = xr[tid + j * 256]; s += v[j]; q += v[j] * v[j]; }
#pragma unroll
  for (int m = 1; m <= 32; m <<= 1) { s += __shfl_xor(s, m); q += __shfl_xor(q, m); }
  __shared__ float red[2][4];
  const int w = tid >> 6;
  if ((tid & 63) == 0) { red[0][w] = s; red[1][w] = q; }
  __syncthreads();
  s = red[0][0] + red[0][1] + red[0][2] + red[0][3];
  q = red[1][0] + red[1][1] + red[1][2] + red[1][3];
  const float mean = s * (1.f / Cc);
  const float var = q * (1.f / Cc) - mean * mean;
  const float rstd = rsqrtf(var + 1e-5f);
#pragma unroll
  for (int j = 0; j < 4; ++j) {
    int c = tid + j * 256;
    out[(size_t)row * Cc + c] = f32_bf16((v[j] - mean) * rstd * g[c] + b[c]);
  }
}

// ---------------------------------------------------------------------------
// LN2 + router (all-f32 router math to avoid top-k tie flips).
// ---------------------------------------------------------------------------
__global__ __launch_bounds__(256) void ln2_router_kernel(
    const float* __restrict__ x, const float* __restrict__ g,
    const float* __restrict__ b, const float* __restrict__ rw,
    unsigned short* __restrict__ out, int* __restrict__ tki, float* __restrict__ tkp) {
  const int row = blockIdx.x;
  const int tid = threadIdx.x;
  const float* xr = x + (size_t)row * Cc;
  float v[4]; float s = 0.f, q = 0.f;
#pragma unroll
  for (int j = 0; j < 4; ++j) { v[j] = xr[tid + j * 256]; s += v[j]; q += v[j] * v[j]; }
#pragma unroll
  for (int m = 1; m <= 32; m <<= 1) { s += __shfl_xor(s, m); q += __shfl_xor(q, m); }
  __shared__ float red[2][4];
  const int w = tid >> 6;
  if ((tid & 63) == 0) { red[0][w] = s; red[1][w] = q; }
  __syncthreads();
  s = red[0][0] + red[0][1] + red[0][2] + red[0][3];
  q = red[1][0] + red[1][1] + red[1][2] + red[1][3];
  const float mean = s * (1.f / Cc);
  const float var = q * (1.f / Cc) - mean * mean;
  const float rstd = rsqrtf(var + 1e-5f);
  float lg[8] = {0.f, 0.f, 0.f, 0.f, 0.f, 0.f, 0.f, 0.f};
#pragma unroll
  for (int j = 0; j < 4; ++j) {
    int c = tid + j * 256;
    float nv = (v[j] - mean) * rstd * g[c] + b[c];
    out[(size_t)row * Cc + c] = f32_bf16(nv);
    const float* rwc = rw + c * 8;
#pragma unroll
    for (int e = 0; e < 8; ++e) lg[e] += nv * rwc[e];
  }
#pragma unroll
  for (int m = 1; m <= 32; m <<= 1) {
#pragma unroll
    for (int e = 0; e < 8; ++e) lg[e] += __shfl_xor(lg[e], m);
  }
  __shared__ float rl[4][8];
  if ((tid & 63) == 0) {
#pragma unroll
    for (int e = 0; e < 8; ++e) rl[w][e] = lg[e];
  }
  __syncthreads();
  if (tid == 0) {
    float L[8];
#pragma unroll
    for (int e = 0; e < 8; ++e) L[e] = rl[0][e] + rl[1][e] + rl[2][e] + rl[3][e];
    int i1 = 0;
    for (int e = 1; e < 8; ++e) if (L[e] > L[i1]) i1 = e;
    int i2 = (i1 == 0) ? 1 : 0;
    for (int e = 0; e < 8; ++e) if (e != i1 && L[e] > L[i2]) i2 = e;
    float e2 = expf(L[i2] - L[i1]);
    float inv = 1.f / (1.f + e2);
    tki[row * 2] = i1; tki[row * 2 + 1] = i2;
    tkp[row * 2] = inv; tkp[row * 2 + 1] = e2 * inv;
  }
}

// ---------------------------------------------------------------------------
// Routing: counts -> offsets -> slot assignment (slots compact by expert).
// ---------------------------------------------------------------------------
__global__ __launch_bounds__(256) void count_kernel(
    const int* __restrict__ tki, int* __restrict__ counts) {
  int n = blockIdx.x * 256 + threadIdx.x;
  if (n >= Nc) return;
  atomicAdd(&counts[tki[n * 2]], 1);
  atomicAdd(&counts[tki[n * 2 + 1]], 1);
}

__global__ void scan_kernel(const int* __restrict__ counts,
                            int* __restrict__ eoff, int* __restrict__ cursor) {
  if (threadIdx.x == 0 && blockIdx.x == 0) {
    int s = 0;
    for (int e = 0; e < Ec; ++e) { eoff[e] = s; cursor[e] = s; s += counts[e]; }
    eoff[Ec] = s;
  }
}

__global__ __launch_bounds__(256) void assign_kernel(
    const int* __restrict__ tki, const float* __restrict__ tkp,
    int* __restrict__ cursor, int* __restrict__ slot_tok,
    float* __restrict__ slot_gate) {
  int n = blockIdx.x * 256 + threadIdx.x;
  if (n >= Nc) return;
#pragma unroll
  for (int kk = 0; kk < 2; ++kk) {
    int e = tki[n * 2 + kk];
    int slot = atomicAdd(&cursor[e], 1);
    slot_tok[slot] = n;
    slot_gate[slot] = tkp[n * 2 + kk];
  }
}

// ---------------------------------------------------------------------------
// 128x128-tile GEMM, BK=32, double-buffered LDS, 2-phase pipeline.
// XCD-chunked tile swizzle: linear id -> (e, col, row), row fastest, col next,
// expert outer; chunk == tiles/XCD. For MoE GEMMs chunk == tiles/expert, so
// each XCD owns exactly one expert (weights stay in its private L2).
// MODE: 0=QKV scatter (V transposed), 1=proj+residual->f32,
//       2=fc gather +gelu->he(bf16), 3=pj*gate atomicAdd->out
// ---------------------------------------------------------------------------
struct GArgs {
  const unsigned short* A;    // bf16
  const unsigned short* Bt;   // bf16 [N][K] (+ e*Bstride)
  const float* bias;          // f32 [N]     (+ e*biasStride)
  int M, N, K, lda;
  size_t Bstride; int biasStride;
  const int* eoff;            // [E+1] slot offsets (MODE 2/3)
  const int* slot_tok;        // slot -> token (MODE 2/3)
  const float* slot_gate;     // MODE 3
  float* outF;                // MODE 1: out, MODE 3: out (atomic)
  const float* resid;         // MODE 1
  unsigned short* outB;       // MODE 2: he ; MODE 0: q
  unsigned short* outK;       // MODE 0: k
  unsigned short* outV;       // MODE 0: v^T [B,H,D,T]
};

template <int MODE>
__global__ __launch_bounds__(256) void gemm128(GArgs g) {
  // ---- XCD-chunked swizzle (grid: x=colblocks NCb, y=32 rowblocks, z=NE) ----
  const int NCb = gridDim.x, NE = gridDim.z;
  const int orig = blockIdx.x + NCb * (blockIdx.y + 32 * blockIdx.z);
  const int chunk = NCb * 4 * NE;               // total/8
  const int t_ = (orig & 7) * chunk + (orig >> 3);
  const int per_e = NCb * 32;
  const int e = t_ / per_e;
  const int rem = t_ - e * per_e;
  const int cb = rem >> 5, rb = rem & 31;       // row fastest, col next

  int s0 = 0, Meff = g.M;
  if constexpr (MODE == 2 || MODE == 3) {
    s0 = g.eoff[e];
    Meff = g.eoff[e + 1] - s0;
  }
  const int row0 = rb * 128;
  if (row0 >= Meff) return;
  const int col0 = cb * 128;

  __shared__ __align__(16) unsigned short As[2][4096];
  __shared__ __align__(16) unsigned short Bs[2][4096];

  const int tid = threadIdx.x;
  const int lane = tid & 63, w = tid >> 6;
  const int wr = w >> 1, wc = w & 1;
  const int fr = lane & 15, fg = lane >> 4;

  const unsigned short* Bt = g.Bt + (size_t)e * g.Bstride;
  const float* bias = g.bias + (size_t)e * g.biasStride;

  // per-issue global addresses (element offsets), k0 added per step
  size_t aaddr[2], baddr[2];
#pragma unroll
  for (int i = 0; i < 2; ++i) {
    int pos = i * 256 + tid;
    int r = pos >> 2, c8 = (pos & 3) * 8;
    int gr = row0 + r;
    if (gr >= Meff) gr = Meff - 1;            // clamp (partial expert tiles)
    int srcrow;
    if constexpr (MODE == 2) srcrow = g.slot_tok[s0 + gr];
    else if constexpr (MODE == 3) srcrow = s0 + gr;
    else srcrow = gr;
    aaddr[i] = (size_t)srcrow * g.lda + c8;
    baddr[i] = (size_t)(col0 + r) * g.K + c8;
  }

  auto STAGE = [&](int buf, int k0) {
#pragma unroll
    for (int i = 0; i < 2; ++i) {
      GLOAD_LDS16(g.A + aaddr[i] + k0, &As[buf][i * 2048 + w * 512]);
      GLOAD_LDS16(Bt + baddr[i] + k0, &Bs[buf][i * 2048 + w * 512]);
    }
  };

  f32x4 acc[4][4] = {};
  const int nt = g.K / 32;

  STAGE(0, 0);
  SYNC_VM0();
  int cur = 0;

  for (int t = 0; t < nt; ++t) {
    if (t + 1 < nt) STAGE(cur ^ 1, (t + 1) * 32);
    b16v8 af[4], bfr[4];
#pragma unroll
    for (int mi = 0; mi < 4; ++mi)
      af[mi] = *(const b16v8*)&As[cur][(wr * 64 + mi * 16 + fr) * 32 + fg * 8];
#pragma unroll
    for (int ni = 0; ni < 4; ++ni)
      bfr[ni] = *(const b16v8*)&Bs[cur][(wc * 64 + ni * 16 + fr) * 32 + fg * 8];
#pragma unroll
    for (int mi = 0; mi < 4; ++mi)
#pragma unroll
      for (int ni = 0; ni < 4; ++ni)
        acc[mi][ni] = MFMA(af[mi], bfr[ni], acc[mi][ni]);
    if (t + 1 < nt) {
      SYNC_VM0();
      cur ^= 1;
    }
  }

#pragma unroll
  for (int mi = 0; mi < 4; ++mi) {
#pragma unroll
    for (int ni = 0; ni < 4; ++ni) {
#pragma unroll
      for (int rr = 0; rr < 4; ++rr) {
        int row = row0 + wr * 64 + mi * 16 + fg * 4 + rr;  // D: row=(lane>>4)*4+reg
        int col = col0 + wc * 64 + ni * 16 + fr;           // D: col=lane&15
        if (row >= Meff) continue;
        float val = acc[mi][ni][rr] + bias[col];
        if constexpr (MODE == 0) {
          int bb = row >> 11, tt = row & (Tc - 1);
          int which = col >> 10, cj = col & (Cc - 1);
          int hd = cj >> 6, d = cj & 63;
          if (which == 0)
            g.outB[(((size_t)(bb * Hc + hd)) * Tc + tt) * Dc + d] = f32_bf16(val);
          else if (which == 1)
            g.outK[(((size_t)(bb * Hc + hd)) * Tc + tt) * Dc + d] = f32_bf16(val);
          else
            g.outV[(((size_t)(bb * Hc + hd)) * Dc + d) * Tc + tt] = f32_bf16(val);
        } else if constexpr (MODE == 1) {
          size_t o = (size_t)row * g.N + col;
          g.outF[o] = val + g.resid[o];
        } else if constexpr (MODE == 2) {
          g.outB[(size_t)(s0 + row) * g.N + col] = f32_bf16(gelu_f(val));
        } else {
          int tok = g.slot_tok[s0 + row];
          atomicAdd(&g.outF[(size_t)tok * Cc + col], g.slot_gate[s0 + row] * val);
        }
      }
    }
  }
}

// ---------------------------------------------------------------------------
// Flash-style causal attention. Block = 4 waves, 64 q-rows (16 per wave).
// K tile LDS [kv][d]; V^T tile LDS [d][kv] from pre-transposed vbuf.
// Softmax in exp2 domain (hardware v_exp_f32). P via per-wave LDS round-trip.
// ---------------------------------------------------------------------------
__global__ __launch_bounds__(256) void attn_kernel(
    const unsigned short* __restrict__ q, const unsigned short* __restrict__ k,
    const unsigned short* __restrict__ v, unsigned short* __restrict__ y) {
  const int qt = blockIdx.x, bh = blockIdx.y;
  const int qbase = qt * 64;
  __shared__ __align__(16) unsigned short ldsK[64][72];
  __shared__ __align__(16) unsigned short ldsVT[64][72];     // [d][kv]
  __shared__ __align__(16) unsigned short ldsP[4][16][72];
  const int tid = threadIdx.x, lane = tid & 63, w = tid >> 6;
  const int fr = lane & 15, fg = lane >> 4;
  const size_t base = (size_t)bh * Tc * Dc;
  const int qrow = qbase + w * 16 + fr;
  b16v8 qa0 = *(const b16v8*)(q + base + (size_t)qrow * Dc + fg * 8);
  b16v8 qa1 = *(const b16v8*)(q + base + (size_t)qrow * Dc + 32 + fg * 8);
  float m[4], lsum[4] = {0.f, 0.f, 0.f, 0.f};
#pragma unroll
  for (int r = 0; r < 4; ++r) m[r] = -3.0e38f;
  f32x4 oacc[4] = {};
  constexpr float SC = 0.125f * LOG2E;   // (1/sqrt(64)) * log2(e)

  for (int kb = 0; kb <= qbase; kb += 64) {
    __syncthreads();
#pragma unroll
    for (int i = 0; i < 2; ++i) {
      int pos = i * 256 + tid;
      int r = pos >> 3, cb = (pos & 7) * 8;
      *(uint4*)&ldsK[r][cb]  = *(const uint4*)(k + base + (size_t)(kb + r) * Dc + cb);
      *(uint4*)&ldsVT[r][cb] = *(const uint4*)(v + base + (size_t)r * Tc + kb + cb);
    }
    __syncthreads();

    f32x4 s[4];
#pragma unroll
    for (int ni = 0; ni < 4; ++ni) {
      b16v8 kb0 = *(const b16v8*)&ldsK[ni * 16 + fr][fg * 8];
      b16v8 kb1 = *(const b16v8*)&ldsK[ni * 16 + fr][32 + fg * 8];
      f32x4 z = {};
      z = MFMA(qa0, kb0, z);
      z = MFMA(qa1, kb1, z);
      s[ni] = z;
    }
    const bool diag = (kb == qbase);
#pragma unroll
    for (int ni = 0; ni < 4; ++ni) {
#pragma unroll
      for (int r = 0; r < 4; ++r) {
        float sv = s[ni][r] * SC;       // log2-domain scores
        if (diag) {
          int qr = w * 16 + fg * 4 + r;
          int kc = ni * 16 + fr;
          if (kc > qr) sv = -3.0e38f;
        }
        s[ni][r] = sv;
      }
    }
#pragma unroll
    for (int r = 0; r < 4; ++r) {
      float mx = fmaxf(fmaxf(s[0][r], s[1][r]), fmaxf(s[2][r], s[3][r]));
#pragma unroll
      for (int msk = 1; msk <= 8; msk <<= 1) mx = fmaxf(mx, __shfl_xor(mx, msk));
      float mnew = fmaxf(m[r], mx);
      float alpha = __builtin_amdgcn_exp2f(m[r] - mnew);
      float psum = 0.f;
#pragma unroll
      for (int ni = 0; ni < 4; ++ni) {
        float pp = __builtin_amdgcn_exp2f(s[ni][r] - mnew);
        s[ni][r] = pp;
        psum += pp;
      }
#pragma unroll
      for (int msk = 1; msk <= 8; msk <<= 1) psum += __shfl_xor(psum, msk);
      lsum[r] = lsum[r] * alpha + psum;
      m[r] = mnew;
#pragma unroll
      for (int ni = 0; ni < 4; ++ni) {
        oacc[ni][r] = oacc[ni][r] * alpha;
        ldsP[w][fg * 4 + r][ni * 16 + fr] = f32_bf16(s[ni][r]);
      }
    }
    asm volatile("s_waitcnt lgkmcnt(0)" ::: "memory");
    __builtin_amdgcn_sched_barrier(0);
    b16v8 pa0 = *(const b16v8*)&ldsP[w][fr][fg * 8];
    b16v8 pa1 = *(const b16v8*)&ldsP[w][fr][32 + fg * 8];
#pragma unroll
    for (int ni = 0; ni < 4; ++ni) {
      b16v8 vb0 = *(const b16v8*)&ldsVT[ni * 16 + fr][fg * 8];
      b16v8 vb1 = *(const b16v8*)&ldsVT[ni * 16 + fr][32 + fg * 8];
      oacc[ni] = MFMA(pa0, vb0, oacc[ni]);
      oacc[ni] = MFMA(pa1, vb1, oacc[ni]);
    }
  }

  const int bb = bh >> 4, hh = bh & 15;
#pragma unroll
  for (int r = 0; r < 4; ++r) {
    float rl = __builtin_amdgcn_rcpf(lsum[r]);
#pragma unroll
    for (int ni = 0; ni < 4; ++ni) {
      int t = qbase + w * 16 + fg * 4 + r;
      int d = ni * 16 + fr;
      y[((size_t)(bb * Tc + t)) * Cc + hh * Dc + d] = f32_bf16(oacc[ni][r] * rl);
    }
  }
}

// ---------------------------------------------------------------------------
extern "C" void kernel_launch(void* const* d_in, const int* in_sizes, int n_in,
                              void* d_out, int out_size, void* d_ws, size_t ws_size,
                              hipStream_t stream) {
  const float* x        = (const float*)d_in[0];
  const float* ln1_g    = (const float*)d_in[1];
  const float* ln1_b    = (const float*)d_in[2];
  const float* ln2_g    = (const float*)d_in[3];
  const float* ln2_b    = (const float*)d_in[4];
  const float* attn_w   = (const float*)d_in[5];
  const float* attn_b   = (const float*)d_in[6];
  const float* proj_w   = (const float*)d_in[7];
  const float* proj_b   = (const float*)d_in[8];
  const float* router_w = (const float*)d_in[9];
  const float* fc_w     = (const float*)d_in[10];
  const float* fc_b     = (const float*)d_in[11];
  const float* pj_w     = (const float*)d_in[12];
  const float* pj_b     = (const float*)d_in[13];
  float* out = (float*)d_out;

  char* ws = (char*)d_ws;
  size_t off = 0;
  auto alloc = [&](size_t bytes) -> void* {
    void* p = ws + off;
    off = (off + bytes + 255) & ~(size_t)255;
    return p;
  };
  unsigned short* attn_wT = (unsigned short*)alloc((size_t)3 * Cc * Cc * 2);      // [3C][C]
  unsigned short* proj_wT = (unsigned short*)alloc((size_t)Cc * Cc * 2);          // [C][C]
  unsigned short* fc_wT   = (unsigned short*)alloc((size_t)Ec * HIDc * Cc * 2);   // [E][HID][C]
  unsigned short* pj_wT   = (unsigned short*)alloc((size_t)Ec * Cc * HIDc * 2);   // [E][C][HID]
  unsigned short* h    = (unsigned short*)alloc((size_t)Nc * Cc * 2);
  unsigned short* qb   = (unsigned short*)alloc((size_t)Nc * Cc * 2);   // [B,H,T,D]
  unsigned short* kbuf = (unsigned short*)alloc((size_t)Nc * Cc * 2);   // [B,H,T,D]
  unsigned short* vbuf = (unsigned short*)alloc((size_t)Nc * Cc * 2);   // [B,H,D,T]
  unsigned short* ybuf = (unsigned short*)alloc((size_t)Nc * Cc * 2);   // [N,C]
  unsigned short* he   = (unsigned short*)alloc((size_t)NPAIR * HIDc * 2);
  int*   tki      = (int*)alloc((size_t)Nc * 2 * 4);
  float* tkp      = (float*)alloc((size_t)Nc * 2 * 4);
  int*   counts   = (int*)alloc(Ec * 4);
  int*   eoff     = (int*)alloc((Ec + 1) * 4);
  int*   cursor   = (int*)alloc(Ec * 4);
  int*   slot_tok = (int*)alloc((size_t)NPAIR * 4);
  float* slot_gate= (float*)alloc((size_t)NPAIR * 4);
  (void)ws_size; (void)in_sizes; (void)n_in; (void)out_size;

  // 0) weight pre-transpose/convert
  convT_kernel<<<dim3(3 * Cc / 32, Cc / 32, 1), 256, 0, stream>>>(attn_w, attn_wT, Cc, 3 * Cc);
  convT_kernel<<<dim3(Cc / 32, Cc / 32, 1), 256, 0, stream>>>(proj_w, proj_wT, Cc, Cc);
  convT_kernel<<<dim3(HIDc / 32, Cc / 32, Ec), 256, 0, stream>>>(fc_w, fc_wT, Cc, HIDc);
  convT_kernel<<<dim3(Cc / 32, HIDc / 32, Ec), 256, 0, stream>>>(pj_w, pj_wT, HIDc, Cc);

  // 1) LN1
  ln1_kernel<<<Nc, 256, 0, stream>>>(x, ln1_g, ln1_b, h);

  // 2) QKV GEMM -> q/k [B,H,T,D], v^T [B,H,D,T]
  {
    GArgs a = {};
    a.A = h; a.Bt = attn_wT; a.bias = attn_b;
    a.M = Nc; a.N = 3 * Cc; a.K = Cc; a.lda = Cc;
    a.outB = qb; a.outK = kbuf; a.outV = vbuf;
    gemm128<0><<<dim3(3 * Cc / 128, Nc / 128, 1), 256, 0, stream>>>(a);
  }

  // 3) causal attention -> y [N,C] bf16
  attn_kernel<<<dim3(Tc / 64, Bc * Hc), 256, 0, stream>>>(qb, kbuf, vbuf, ybuf);

  // 4) proj + residual -> d_out (f32)
  {
    GArgs p = {};
    p.A = ybuf; p.Bt = proj_wT; p.bias = proj_b;
    p.M = Nc; p.N = Cc; p.K = Cc; p.lda = Cc;
    p.outF = out; p.resid = x;
    gemm128<1><<<dim3(Cc / 128, Nc / 128, 1), 256, 0, stream>>>(p);
  }

  // 5) LN2 + router -> h (bf16), top-2
  ln2_router_kernel<<<Nc, 256, 0, stream>>>(out, ln2_g, ln2_b, router_w, h, tki, tkp);

  // 6) routing lists (slot-compacted pairs)
  hipMemsetAsync(counts, 0, Ec * sizeof(int), stream);
  count_kernel<<<(Nc + 255) / 256, 256, 0, stream>>>(tki, counts);
  scan_kernel<<<1, 64, 0, stream>>>(counts, eoff, cursor);
  assign_kernel<<<(Nc + 255) / 256, 256, 0, stream>>>(tki, tkp, cursor, slot_tok, slot_gate);

  // 7) fc (expert==XCD) -> he [NPAIR][HID] bf16 w/ GELU
  {
    GArgs f = {};
    f.A = h; f.Bt = fc_wT; f.bias = fc_b;
    f.M = Nc; f.N = HIDc; f.K = Cc; f.lda = Cc;
    f.Bstride = (size_t)HIDc * Cc; f.biasStride = HIDc;
    f.eoff = eoff; f.slot_tok = slot_tok;
    f.outB = he;
    gemm128<2><<<dim3(HIDc / 128, Nc / 128, Ec), 256, 0, stream>>>(f);
  }

  // 8) pj (expert==XCD) -> gate-weighted atomicAdd into d_out (bias incl.)
  {
    GArgs pj = {};
    pj.A = he; pj.Bt = pj_wT; pj.bias = pj_b;
    pj.M = Nc; pj.N = Cc; pj.K = HIDc; pj.lda = HIDc;
    pj.Bstride = (size_t)Cc * HIDc; pj.biasStride = Cc;
    pj.eoff = eoff; pj.slot_tok = slot_tok; pj.slot_gate = slot_gate;
    pj.outF = out;
    gemm128<3><<<dim3(Cc / 128, Nc / 128, Ec), 256, 0, stream>>>(pj);
  }
}